// Round 1
// baseline (312.777 us; speedup 1.0000x reference)
//
#include <hip/hip_runtime.h>

#define H_ 8
#define DK 64
#define LQ 2048
#define LK 2048
#define BS 2
#define DM 512

typedef _Float16 f16;
typedef _Float16 f16x8 __attribute__((ext_vector_type(8)));
typedef float f32x4 __attribute__((ext_vector_type(4)));

#define LS 72  // LDS row stride in f16: 144B = 16B-aligned, 2-way bank max on row-indexed b128 reads

// ---------------- mask bit-pack: [b][q][k] int32 -> [b][q][k/32] bits ----------------
__global__ __launch_bounds__(256) void maskpack_k(const int* __restrict__ mask,
                                                  unsigned* __restrict__ mp) {
  int w = blockIdx.x * 256 + threadIdx.x;  // word index over BS*LQ*64
  const int* src = mask + (size_t)w * 32;
  unsigned bits = 0;
#pragma unroll
  for (int i = 0; i < 32; i++) bits |= (src[i] != 0 ? 1u : 0u) << i;
  mp[w] = bits;
}

// ---------------- generic 512-K GEMM: C = (X@W + bias) * scale ----------------
// IN_F16: X is f16 (else f32). OUT_SCATTER: store f16 to [b][h][l][d], else f32 to [m][n].
template <int IN_F16, int OUT_SCATTER>
__global__ __launch_bounds__(256) void gemm512_k(const void* __restrict__ Xv,
                                                 const float* __restrict__ W,
                                                 const float* __restrict__ bias,
                                                 void* __restrict__ Out, float scale) {
  __shared__ f16 As[64][LS];  // [m][k]
  __shared__ f16 Bt[64][LS];  // [n][k]  (W staged transposed)
  const int tid = threadIdx.x;
  const int lane = tid & 63, w = tid >> 6;
  const int wr = w >> 1, wc = w & 1;        // wave 2x2 -> 32x32 per wave
  const int fr = lane & 15, fs = lane >> 4; // frag row / k-slice
  const int m0 = blockIdx.x * 64, n0 = blockIdx.y * 64;

  f32x4 acc[2][2] = {};

  for (int k0 = 0; k0 < DM; k0 += 64) {
    __syncthreads();
    {
      int m = tid >> 2, c = tid & 3;
#pragma unroll
      for (int pp = 0; pp < 2; pp++) {
        int cc = c + pp * 4;  // 8-f16 chunk 0..7
        if (IN_F16) {
          const f16* X = (const f16*)Xv;
          *(f16x8*)&As[m][cc * 8] = *(const f16x8*)(X + (size_t)(m0 + m) * DM + k0 + cc * 8);
        } else {
          const float* X = (const float*)Xv;
          const float* p = X + (size_t)(m0 + m) * DM + k0 + cc * 8;
          f32x4 v0 = *(const f32x4*)p;
          f32x4 v1 = *(const f32x4*)(p + 4);
          f16x8 hv;
#pragma unroll
          for (int i = 0; i < 4; i++) { hv[i] = (f16)v0[i]; hv[i + 4] = (f16)v1[i]; }
          *(f16x8*)&As[m][cc * 8] = hv;
        }
      }
#pragma unroll
      for (int pp = 0; pp < 4; pp++) {
        int kk = (tid >> 4) + pp * 16, n4 = (tid & 15) * 4;
        f32x4 wv = *(const f32x4*)(W + (size_t)(k0 + kk) * DM + n0 + n4);
#pragma unroll
        for (int i = 0; i < 4; i++) Bt[n4 + i][kk] = (f16)wv[i];
      }
    }
    __syncthreads();
#pragma unroll
    for (int kc = 0; kc < 2; kc++) {
      f16x8 a[2], b[2];
#pragma unroll
      for (int mi = 0; mi < 2; mi++)
        a[mi] = *(const f16x8*)&As[wr * 32 + mi * 16 + fr][kc * 32 + fs * 8];
#pragma unroll
      for (int ni = 0; ni < 2; ni++)
        b[ni] = *(const f16x8*)&Bt[wc * 32 + ni * 16 + fr][kc * 32 + fs * 8];
#pragma unroll
      for (int mi = 0; mi < 2; mi++)
#pragma unroll
        for (int ni = 0; ni < 2; ni++)
          acc[mi][ni] =
              __builtin_amdgcn_mfma_f32_16x16x32_f16(a[mi], b[ni], acc[mi][ni], 0, 0, 0);
    }
  }

#pragma unroll
  for (int mi = 0; mi < 2; mi++)
#pragma unroll
    for (int ni = 0; ni < 2; ni++) {
      int gcol = n0 + wc * 32 + ni * 16 + fr;
      float bb = bias[gcol];
#pragma unroll
      for (int i = 0; i < 4; i++) {
        int grow = m0 + wr * 32 + mi * 16 + fs * 4 + i;  // C row=(lane>>4)*4+i, col=lane&15
        float val = (acc[mi][ni][i] + bb) * scale;
        if (OUT_SCATTER) {
          int b_ = grow >> 11, l = grow & (LQ - 1);
          int h_ = gcol >> 6, d = gcol & 63;
          ((f16*)Out)[((size_t)(b_ * H_ + h_) * LQ + l) * DK + d] = (f16)val;
        } else {
          ((float*)Out)[(size_t)grow * DM + gcol] = val;
        }
      }
    }
}

// ---------------- R[bh,q,r] = dot(qp_f16[bh,q,:], rpe[r,:])  (qp prescaled by 1/8) ----------
__global__ __launch_bounds__(256) void relR_k(const f16* __restrict__ qp,
                                              const float* __restrict__ rpe,
                                              float* __restrict__ R) {
  int row = blockIdx.x * 4 + (threadIdx.x >> 6);  // bh*LQ + q
  int lane = threadIdx.x & 63;
  float qv = (float)qp[(size_t)row * DK + lane];
  const float* rp = rpe + lane;
  for (int r = 0; r < 33; r++) {
    float v = qv * rp[r * DK];
    v += __shfl_xor(v, 1);
    v += __shfl_xor(v, 2);
    v += __shfl_xor(v, 4);
    v += __shfl_xor(v, 8);
    v += __shfl_xor(v, 16);
    v += __shfl_xor(v, 32);
    if (lane == 0) R[(size_t)row * 34 + r] = v;
  }
}

// ---------------- fused attention: scores -> softmax -> attn out + PV -> concat ----------
__global__ __launch_bounds__(256) void attn_k(const f16* __restrict__ qp,
                                              const f16* __restrict__ kp,
                                              const f16* __restrict__ vp,
                                              const float* __restrict__ R,
                                              const unsigned* __restrict__ mp,
                                              float* __restrict__ attn,
                                              f16* __restrict__ concat) {
  __shared__ f16 Ks[64][LS];       // K-tile [k][d]
  __shared__ f16 Vt[64][LS];       // V-tile transposed [d][k]
  __shared__ f16 Pl[4][16][LS];    // per-wave P tile [q][k]
  __shared__ float Rl[64][34];     // R rows for this q-block
  __shared__ unsigned Ml[64][64];  // packed mask rows
  const int tid = threadIdx.x, lane = tid & 63, w = tid >> 6;
  const int fr = lane & 15, fs = lane >> 4;
  const int bh = blockIdx.y, b = bh >> 3, h = bh & 7;
  const int q0 = blockIdx.x * 64;
  const f16* Qb = qp + ((size_t)bh * LQ + q0) * DK;
  const f16* Kb = kp + (size_t)bh * LQ * DK;
  const f16* Vb = vp + (size_t)bh * LQ * DK;

  for (int idx = tid; idx < 64 * 34; idx += 256) {
    int r = idx % 34, qq = idx / 34;
    Rl[qq][r] = R[((size_t)bh * LQ + q0 + qq) * 34 + r];  // r=33 pad is unused garbage
  }
  for (int idx = tid; idx < 64 * 64; idx += 256) {
    int wd = idx & 63, qq = idx >> 6;
    Ml[qq][wd] = mp[((size_t)b * LQ + q0 + qq) * 64 + wd];
  }

  // Q fragments held for the whole kernel (wave w owns q rows w*16..w*16+15)
  f16x8 qa[2];
#pragma unroll
  for (int h2 = 0; h2 < 2; h2++)
    qa[h2] = *(const f16x8*)(Qb + (size_t)(w * 16 + fr) * DK + h2 * 32 + fs * 8);

  // ---- sweep 1: row sums ----
  float psum[4] = {0.f, 0.f, 0.f, 0.f};
  for (int kt = 0; kt < LK; kt += 64) {
    __syncthreads();
    {
      int r = tid >> 2, c = tid & 3;
#pragma unroll
      for (int pp = 0; pp < 2; pp++) {
        int cc = c + pp * 4;
        *(f16x8*)&Ks[r][cc * 8] = *(const f16x8*)(Kb + (size_t)(kt + r) * DK + cc * 8);
      }
    }
    __syncthreads();
#pragma unroll
    for (int cb = 0; cb < 4; cb++) {
      f32x4 s = {};
#pragma unroll
      for (int h2 = 0; h2 < 2; h2++) {
        f16x8 bf = *(const f16x8*)&Ks[cb * 16 + fr][h2 * 32 + fs * 8];
        s = __builtin_amdgcn_mfma_f32_16x16x32_f16(qa[h2], bf, s, 0, 0, 0);
      }
      int kk = kt + cb * 16 + fr;
#pragma unroll
      for (int i = 0; i < 4; i++) {
        int qq = w * 16 + fs * 4 + i;
        int gq = q0 + qq;
        int dd = kk - gq;
        dd = dd < -16 ? -16 : (dd > 16 ? 16 : dd);
        float sc = s[i] + Rl[qq][dd + 16];
        unsigned mw = Ml[qq][kk >> 5];
        float pv = ((mw >> (kk & 31)) & 1u) ? __expf(sc) : 0.f;
        psum[i] += pv;
      }
    }
  }
  float inv[4];
#pragma unroll
  for (int i = 0; i < 4; i++) {
    float v = psum[i];
    v += __shfl_xor(v, 1);
    v += __shfl_xor(v, 2);
    v += __shfl_xor(v, 4);
    v += __shfl_xor(v, 8);
    inv[i] = 1.f / v;
  }

  // ---- sweep 2: recompute scores, write normalized attn, accumulate PV ----
  f32x4 oacc[4] = {};
  for (int kt = 0; kt < LK; kt += 64) {
    __syncthreads();
    {
      int r = tid >> 2, c = tid & 3;
#pragma unroll
      for (int pp = 0; pp < 2; pp++) {
        int cc = c + pp * 4;
        *(f16x8*)&Ks[r][cc * 8] = *(const f16x8*)(Kb + (size_t)(kt + r) * DK + cc * 8);
      }
      int d = tid & 63, kg = tid >> 6;
#pragma unroll
      for (int i = 0; i < 16; i++) {
        int k2 = kg * 16 + i;
        Vt[d][k2] = Vb[(size_t)(kt + k2) * DK + d];
      }
    }
    __syncthreads();
#pragma unroll
    for (int cb = 0; cb < 4; cb++) {
      f32x4 s = {};
#pragma unroll
      for (int h2 = 0; h2 < 2; h2++) {
        f16x8 bf = *(const f16x8*)&Ks[cb * 16 + fr][h2 * 32 + fs * 8];
        s = __builtin_amdgcn_mfma_f32_16x16x32_f16(qa[h2], bf, s, 0, 0, 0);
      }
      int kk = kt + cb * 16 + fr;
#pragma unroll
      for (int i = 0; i < 4; i++) {
        int qq = w * 16 + fs * 4 + i;
        int gq = q0 + qq;
        int dd = kk - gq;
        dd = dd < -16 ? -16 : (dd > 16 ? 16 : dd);
        float sc = s[i] + Rl[qq][dd + 16];
        unsigned mw = Ml[qq][kk >> 5];
        float pv = ((mw >> (kk & 31)) & 1u) ? __expf(sc) * inv[i] : 0.f;
        attn[((size_t)bh * LQ + gq) * LK + kk] = pv;
        Pl[w][fs * 4 + i][cb * 16 + fr] = (f16)pv;
      }
    }
    // PV: oacc[16q][64d] += P(16x64) @ V(64x64). Wave-private Pl => no barrier needed.
#pragma unroll
    for (int ks = 0; ks < 2; ks++) {
      f16x8 pa = *(const f16x8*)&Pl[w][fr][ks * 32 + fs * 8];
#pragma unroll
      for (int db = 0; db < 4; db++) {
        f16x8 vb = *(const f16x8*)&Vt[db * 16 + fr][ks * 32 + fs * 8];
        oacc[db] = __builtin_amdgcn_mfma_f32_16x16x32_f16(pa, vb, oacc[db], 0, 0, 0);
      }
    }
  }

#pragma unroll
  for (int db = 0; db < 4; db++) {
#pragma unroll
    for (int i = 0; i < 4; i++) {
      int gq = q0 + w * 16 + fs * 4 + i;
      concat[((size_t)b * LQ + gq) * DM + h * DK + db * 16 + fr] = (f16)oacc[db][i];
    }
  }
}

extern "C" void kernel_launch(void* const* d_in, const int* in_sizes, int n_in,
                              void* d_out, int out_size, void* d_ws, size_t ws_size,
                              hipStream_t stream) {
  const float* q = (const float*)d_in[0];
  const float* k = (const float*)d_in[1];
  const float* v = (const float*)d_in[2];
  const int* mask = (const int*)d_in[3];
  const float* Wq = (const float*)d_in[4];
  const float* bq = (const float*)d_in[5];
  const float* Wk = (const float*)d_in[6];
  const float* bk = (const float*)d_in[7];
  const float* Wv = (const float*)d_in[8];
  const float* bv = (const float*)d_in[9];
  const float* Wo = (const float*)d_in[10];
  const float* bo = (const float*)d_in[11];
  const float* rpe = (const float*)d_in[12];

  char* ws = (char*)d_ws;
  const size_t SZP = (size_t)BS * H_ * LQ * DK * sizeof(f16);  // 4 MB
  f16* qp = (f16*)(ws + 0 * SZP);
  f16* kp = (f16*)(ws + 1 * SZP);
  f16* vp = (f16*)(ws + 2 * SZP);
  float* R = (float*)(ws + 3 * SZP);                       // BS*H*LQ*34 f32
  unsigned* mp = (unsigned*)(ws + 3 * SZP + 4456448);      // BS*LQ*64 u32
  f16* concat = (f16*)(ws + 3 * SZP + 4456448 + 1048576);  // BS*LQ*DM f16

  float* final_out = (float*)d_out;
  float* attn_out = final_out + (size_t)BS * LQ * DM;

  maskpack_k<<<dim3((BS * LQ * 64) / 256), 256, 0, stream>>>(mask, mp);

  dim3 g1(64, 8);
  gemm512_k<0, 1><<<g1, 256, 0, stream>>>(q, Wq, bq, qp, 0.125f);  // fold 1/sqrt(64)
  gemm512_k<0, 1><<<g1, 256, 0, stream>>>(k, Wk, bk, kp, 1.f);
  gemm512_k<0, 1><<<g1, 256, 0, stream>>>(v, Wv, bv, vp, 1.f);

  relR_k<<<dim3((BS * H_ * LQ) / 4), 256, 0, stream>>>(qp, rpe, R);

  attn_k<<<dim3(LQ / 64, BS * H_), 256, 0, stream>>>(qp, kp, vp, R, mp, attn_out, concat);

  gemm512_k<1, 0><<<g1, 256, 0, stream>>>(concat, Wo, bo, final_out, 1.f);
}

// Round 3
// 258.993 us; speedup vs baseline: 1.2077x; 1.2077x over previous
//
#include <hip/hip_runtime.h>

#define H_ 8
#define DK 64
#define LQ 2048
#define LK 2048
#define BS 2
#define DM 512

typedef _Float16 f16;
typedef _Float16 f16x8 __attribute__((ext_vector_type(8)));
typedef float f32x4 __attribute__((ext_vector_type(4)));

#define LS 72   // f16 LDS row stride for K/V/GEMM tiles (144B)
#define PS 40   // f16 LDS row stride for P half-tiles (80B, 16B aligned)

// ---------------- mask bit-pack via ballot: [b][q][k] int32 -> bits ----------------
// one element per thread; grid MUST cover all BS*LQ*LK elements (32768 blocks).
__global__ __launch_bounds__(256) void maskpack_k(const int* __restrict__ mask,
                                                  unsigned long long* __restrict__ mp64) {
  size_t t = (size_t)blockIdx.x * 256 + threadIdx.x;
  unsigned long long b = __ballot(mask[t] != 0);
  if ((threadIdx.x & 63) == 0) mp64[t >> 6] = b;
}

// ---------------- fused QKV projection GEMM ----------------
// grid (64 m-blocks, 24 n-blocks): n segment 0/1/2 -> Q/K/V.
// Q,K out: f16 scatter [b,h,l,d] (Q prescaled 1/8). V out: f16 transposed [b,h,d,l].
__global__ __launch_bounds__(256, 4) void qkv_k(
    const float* __restrict__ qin, const float* __restrict__ kin, const float* __restrict__ vin,
    const float* __restrict__ Wq, const float* __restrict__ Wk, const float* __restrict__ Wv,
    const float* __restrict__ bq, const float* __restrict__ bk, const float* __restrict__ bv,
    f16* __restrict__ qp, f16* __restrict__ kp, f16* __restrict__ vpt) {
  __shared__ f16 As[64][LS];
  __shared__ f16 Bt[64][LS];
  const int tid = threadIdx.x, lane = tid & 63, w = tid >> 6;
  const int wr = w >> 1, wc = w & 1, fr = lane & 15, fs = lane >> 4;
  const int m0 = blockIdx.x * 64;
  const int n0g = blockIdx.y * 64, seg = n0g >> 9, nn0 = n0g & 511;
  const float* X = seg == 0 ? qin : (seg == 1 ? kin : vin);
  const float* W = seg == 0 ? Wq : (seg == 1 ? Wk : Wv);
  const float* bias = seg == 0 ? bq : (seg == 1 ? bk : bv);
  const float scale = seg == 0 ? 0.125f : 1.0f;

  f32x4 acc[2][2] = {};

  for (int k0 = 0; k0 < DM; k0 += 64) {
    __syncthreads();
    {  // A: 64x64 f32 -> f16 LDS
      int m = tid >> 2, c0 = tid & 3;
#pragma unroll
      for (int pp = 0; pp < 2; pp++) {
        int cc = c0 + pp * 4;
        const float* p = X + (size_t)(m0 + m) * DM + k0 + cc * 8;
        f32x4 v0 = *(const f32x4*)p;
        f32x4 v1 = *(const f32x4*)(p + 4);
        f16x8 hv;
#pragma unroll
        for (int i = 0; i < 4; i++) { hv[i] = (f16)v0[i]; hv[i + 4] = (f16)v1[i]; }
        *(f16x8*)&As[m][cc * 8] = hv;
      }
      // B: W[k0..+64][nn0..+64] -> Bt[n][k]
      int kk0 = tid & 15, nch = tid >> 4;
#pragma unroll
      for (int pp = 0; pp < 4; pp++) {
        int kk = kk0 + 16 * pp;
        f32x4 wv = *(const f32x4*)(W + (size_t)(k0 + kk) * DM + nn0 + nch * 4);
#pragma unroll
        for (int i = 0; i < 4; i++) Bt[nch * 4 + i][kk] = (f16)wv[i];
      }
    }
    __syncthreads();
#pragma unroll
    for (int kc = 0; kc < 2; kc++) {
      f16x8 a[2], b[2];
#pragma unroll
      for (int mi = 0; mi < 2; mi++)
        a[mi] = *(const f16x8*)&As[wr * 32 + mi * 16 + fr][kc * 32 + fs * 8];
#pragma unroll
      for (int ni = 0; ni < 2; ni++)
        b[ni] = *(const f16x8*)&Bt[wc * 32 + ni * 16 + fr][kc * 32 + fs * 8];
#pragma unroll
      for (int mi = 0; mi < 2; mi++)
#pragma unroll
        for (int ni = 0; ni < 2; ni++)
          acc[mi][ni] = __builtin_amdgcn_mfma_f32_16x16x32_f16(a[mi], b[ni], acc[mi][ni], 0, 0, 0);
    }
  }

  const int h = nn0 >> 6, b_ = m0 >> 11, l0 = m0 & (LQ - 1);
  if (seg < 2) {
    f16* out = seg == 0 ? qp : kp;
#pragma unroll
    for (int mi = 0; mi < 2; mi++)
#pragma unroll
      for (int ni = 0; ni < 2; ni++) {
        int d = wc * 32 + ni * 16 + fr;
        float bb = bias[nn0 + d];
#pragma unroll
        for (int i = 0; i < 4; i++) {
          int l = l0 + wr * 32 + mi * 16 + fs * 4 + i;
          out[((size_t)(b_ * H_ + h) * LQ + l) * DK + d] = (f16)((acc[mi][ni][i] + bb) * scale);
        }
      }
  } else {
    // transpose via LDS bounce: T[d][l] reusing As
    __syncthreads();
#pragma unroll
    for (int mi = 0; mi < 2; mi++)
#pragma unroll
      for (int ni = 0; ni < 2; ni++) {
        int d = wc * 32 + ni * 16 + fr;
        float bb = bias[nn0 + d];
#pragma unroll
        for (int i = 0; i < 4; i++) {
          int ml = wr * 32 + mi * 16 + fs * 4 + i;
          As[d][ml] = (f16)(acc[mi][ni][i] + bb);
        }
      }
    __syncthreads();
    int r = tid >> 2;
#pragma unroll
    for (int pp = 0; pp < 2; pp++) {
      int c = (tid & 3) + pp * 4;
      *(f16x8*)(vpt + ((size_t)((b_ * H_ + h) * DK + r)) * LK + l0 + c * 8) =
          *(const f16x8*)&As[r][c * 8];
    }
  }
}

// ---------------- R[bh,q,r] = dot(qp_f16[bh,q,:], rpe[r,:]) (qp prescaled 1/8) ------
__global__ __launch_bounds__(256) void relR_k(const f16* __restrict__ qp,
                                              const float* __restrict__ rpe,
                                              float* __restrict__ R) {
  int row = blockIdx.x * 4 + (threadIdx.x >> 6);
  int lane = threadIdx.x & 63;
  float qv = (float)qp[(size_t)row * DK + lane];
  const float* rp = rpe + lane;
  for (int r = 0; r < 33; r++) {
    float v = qv * rp[r * DK];
    v += __shfl_xor(v, 1);
    v += __shfl_xor(v, 2);
    v += __shfl_xor(v, 4);
    v += __shfl_xor(v, 8);
    v += __shfl_xor(v, 16);
    v += __shfl_xor(v, 32);
    if (lane == 0) R[(size_t)row * 34 + r] = v;
  }
}

// ---------------- fused attention, 8 waves: 4 q-strips x 2 k-halves ----------------
__global__ __launch_bounds__(512, 4) void attn_k(const f16* __restrict__ qp,
                                                 const f16* __restrict__ kp,
                                                 const f16* __restrict__ vpt,
                                                 const float* __restrict__ R,
                                                 const unsigned* __restrict__ mp,
                                                 float* __restrict__ attn,
                                                 f16* __restrict__ concat) {
  __shared__ f16 Ks[64][LS];        // K-tile [k][d]
  __shared__ f16 Vt[64][LS];        // V-tile [d][k] (from vpt, no transpose needed)
  __shared__ f16 Pl[8][16][PS];     // per-wave P half-tile [q][k-half]
  __shared__ float Rl[64][34];
  __shared__ float Ph[2][64];       // psum halves
  __shared__ float Oc[4][16][68];   // oacc combine (wh=1 -> wh=0)
  const int tid = threadIdx.x, lane = tid & 63, w = tid >> 6;
  const int wq = w & 3, wh = w >> 2;
  const int fr = lane & 15, fs = lane >> 4;
  // XCD-aware swizzle: each XCD owns 2 bh values
  const int flat = blockIdx.x + 32 * blockIdx.y;
  const int idx = flat >> 3;
  const int bh = (flat & 7) * 2 + (idx >> 5), q0 = (idx & 31) * 64;
  const int b = bh >> 3, h = bh & 7;
  const f16* Qb = qp + ((size_t)bh * LQ + q0) * DK;
  const f16* Kb = kp + (size_t)bh * LQ * DK;
  const f16* Vb = vpt + (size_t)bh * DK * LK;

  for (int i2 = tid; i2 < 64 * 34; i2 += 512)
    Rl[i2 / 34][i2 % 34] = R[((size_t)bh * LQ + q0 + i2 / 34) * 34 + i2 % 34];
  __syncthreads();

  f16x8 qa[2];
#pragma unroll
  for (int h2 = 0; h2 < 2; h2++)
    qa[h2] = *(const f16x8*)(Qb + (size_t)(wq * 16 + fr) * DK + h2 * 32 + fs * 8);

  int qq[4];
  float rlo[4], rhi[4];
  const unsigned* mprow[4];
#pragma unroll
  for (int i = 0; i < 4; i++) {
    qq[i] = wq * 16 + fs * 4 + i;
    rlo[i] = Rl[qq[i]][0];
    rhi[i] = Rl[qq[i]][32];
    mprow[i] = mp + ((size_t)b * LQ + q0 + qq[i]) * 64;
  }

  // ---- sweep 1: denominator ----
  float psum[4] = {0.f, 0.f, 0.f, 0.f};
  for (int kt = 0; kt < LK; kt += 64) {
    __syncthreads();
    {
      int r = tid >> 3, c = tid & 7;
      *(f16x8*)&Ks[r][c * 8] = *(const f16x8*)(Kb + (size_t)(kt + r) * DK + c * 8);
    }
    __syncthreads();
    f32x4 sv[2];
#pragma unroll
    for (int cbh = 0; cbh < 2; cbh++) {
      int cb = wh * 2 + cbh;
      f32x4 s = {};
#pragma unroll
      for (int h2 = 0; h2 < 2; h2++) {
        f16x8 bf = *(const f16x8*)&Ks[cb * 16 + fr][h2 * 32 + fs * 8];
        s = __builtin_amdgcn_mfma_f32_16x16x32_f16(qa[h2], bf, s, 0, 0, 0);
      }
      sv[cbh] = s;
    }
    unsigned mw[4];
#pragma unroll
    for (int i = 0; i < 4; i++) mw[i] = mprow[i][(kt >> 5) + wh];
    const int dt = kt - q0;
    if (dt <= -128 || dt >= 128) {
#pragma unroll
      for (int cbh = 0; cbh < 2; cbh++)
#pragma unroll
        for (int i = 0; i < 4; i++) {
          float sc = sv[cbh][i] + (dt < 0 ? rlo[i] : rhi[i]);
          float pv = ((mw[i] >> (cbh * 16 + fr)) & 1u) ? __expf(sc) : 0.f;
          psum[i] += pv;
        }
    } else {
#pragma unroll
      for (int cbh = 0; cbh < 2; cbh++)
#pragma unroll
        for (int i = 0; i < 4; i++) {
          int dd = dt + wh * 32 + cbh * 16 + fr - qq[i];
          dd = dd < -16 ? -16 : (dd > 16 ? 16 : dd);
          float sc = sv[cbh][i] + Rl[qq[i]][dd + 16];
          float pv = ((mw[i] >> (cbh * 16 + fr)) & 1u) ? __expf(sc) : 0.f;
          psum[i] += pv;
        }
    }
  }
  // reduce over fr within half, then combine halves via LDS
#pragma unroll
  for (int i = 0; i < 4; i++) {
    float v = psum[i];
    v += __shfl_xor(v, 1);
    v += __shfl_xor(v, 2);
    v += __shfl_xor(v, 4);
    v += __shfl_xor(v, 8);
    psum[i] = v;
  }
  if (fr == 0)
#pragma unroll
    for (int i = 0; i < 4; i++) Ph[wh][qq[i]] = psum[i];
  __syncthreads();
  float inv[4];
#pragma unroll
  for (int i = 0; i < 4; i++) inv[i] = 1.f / (Ph[0][qq[i]] + Ph[1][qq[i]]);

  // ---- sweep 2: recompute, write normalized attn, accumulate PV ----
  f32x4 oacc[4] = {};
  for (int kt = 0; kt < LK; kt += 64) {
    __syncthreads();
    {
      int r = tid >> 3, c = tid & 7;
      *(f16x8*)&Ks[r][c * 8] = *(const f16x8*)(Kb + (size_t)(kt + r) * DK + c * 8);
      *(f16x8*)&Vt[r][c * 8] = *(const f16x8*)(Vb + (size_t)r * LK + kt + c * 8);
    }
    __syncthreads();
    f32x4 sv[2];
#pragma unroll
    for (int cbh = 0; cbh < 2; cbh++) {
      int cb = wh * 2 + cbh;
      f32x4 s = {};
#pragma unroll
      for (int h2 = 0; h2 < 2; h2++) {
        f16x8 bf = *(const f16x8*)&Ks[cb * 16 + fr][h2 * 32 + fs * 8];
        s = __builtin_amdgcn_mfma_f32_16x16x32_f16(qa[h2], bf, s, 0, 0, 0);
      }
      sv[cbh] = s;
    }
    unsigned mw[4];
#pragma unroll
    for (int i = 0; i < 4; i++) mw[i] = mprow[i][(kt >> 5) + wh];
    const int dt = kt - q0;
    if (dt <= -128 || dt >= 128) {
#pragma unroll
      for (int cbh = 0; cbh < 2; cbh++)
#pragma unroll
        for (int i = 0; i < 4; i++) {
          float sc = sv[cbh][i] + (dt < 0 ? rlo[i] : rhi[i]);
          float pv = ((mw[i] >> (cbh * 16 + fr)) & 1u) ? __expf(sc) * inv[i] : 0.f;
          Pl[w][fs * 4 + i][cbh * 16 + fr] = (f16)pv;
        }
    } else {
#pragma unroll
      for (int cbh = 0; cbh < 2; cbh++)
#pragma unroll
        for (int i = 0; i < 4; i++) {
          int dd = dt + wh * 32 + cbh * 16 + fr - qq[i];
          dd = dd < -16 ? -16 : (dd > 16 ? 16 : dd);
          float sc = sv[cbh][i] + Rl[qq[i]][dd + 16];
          float pv = ((mw[i] >> (cbh * 16 + fr)) & 1u) ? __expf(sc) * inv[i] : 0.f;
          Pl[w][fs * 4 + i][cbh * 16 + fr] = (f16)pv;
        }
    }
    // PV over this wave's 32-k half
    {
      f16x8 pa = *(const f16x8*)&Pl[w][fr][fs * 8];
#pragma unroll
      for (int db = 0; db < 4; db++) {
        f16x8 vb = *(const f16x8*)&Vt[db * 16 + fr][wh * 32 + fs * 8];
        oacc[db] = __builtin_amdgcn_mfma_f32_16x16x32_f16(pa, vb, oacc[db], 0, 0, 0);
      }
    }
    // coalesced attn write from Pl (f32x4)
    {
      int r2 = lane >> 2, cq = lane & 3;
      float* arow = attn + ((size_t)bh * LQ + q0 + wq * 16 + r2) * LK + kt + wh * 32 + cq * 8;
      f16x8 pv8 = *(const f16x8*)&Pl[w][r2][cq * 8];
      f32x4 o0 = {(float)pv8[0], (float)pv8[1], (float)pv8[2], (float)pv8[3]};
      f32x4 o1 = {(float)pv8[4], (float)pv8[5], (float)pv8[6], (float)pv8[7]};
      *(f32x4*)(arow) = o0;
      *(f32x4*)(arow + 4) = o1;
    }
  }

  // combine oacc across k-halves, write concat (f16 [b, l, h*64+d])
  __syncthreads();
  if (wh == 1) {
#pragma unroll
    for (int db = 0; db < 4; db++)
#pragma unroll
      for (int i = 0; i < 4; i++) Oc[wq][fs * 4 + i][db * 16 + fr] = oacc[db][i];
  }
  __syncthreads();
  if (wh == 0) {
#pragma unroll
    for (int db = 0; db < 4; db++)
#pragma unroll
      for (int i = 0; i < 4; i++) {
        float val = oacc[db][i] + Oc[wq][fs * 4 + i][db * 16 + fr];
        int gq = q0 + wq * 16 + fs * 4 + i;
        concat[((size_t)b * LQ + gq) * DM + h * DK + db * 16 + fr] = (f16)val;
      }
  }
}

// ---------------- output GEMM, split-K=2, atomic accumulate into zeroed out ------
__global__ __launch_bounds__(256, 4) void ogemm_k(const f16* __restrict__ X,
                                                  const float* __restrict__ W,
                                                  const float* __restrict__ bias,
                                                  float* __restrict__ out) {
  __shared__ f16 As[64][LS];
  __shared__ f16 Bt[64][LS];
  const int tid = threadIdx.x, lane = tid & 63, w = tid >> 6;
  const int wr = w >> 1, wc = w & 1, fr = lane & 15, fs = lane >> 4;
  const int m0 = blockIdx.x * 64, n0 = blockIdx.y * 64, kz = blockIdx.z * 256;

  f32x4 acc[2][2] = {};
  for (int k0 = kz; k0 < kz + 256; k0 += 64) {
    __syncthreads();
    {
      int r = tid >> 2, c0 = tid & 3;
#pragma unroll
      for (int pp = 0; pp < 2; pp++) {
        int c = c0 + pp * 4;
        *(f16x8*)&As[r][c * 8] = *(const f16x8*)(X + (size_t)(m0 + r) * DM + k0 + c * 8);
      }
      int kk0 = tid & 15, nch = tid >> 4;
#pragma unroll
      for (int pp = 0; pp < 4; pp++) {
        int kk = kk0 + 16 * pp;
        f32x4 wv = *(const f32x4*)(W + (size_t)(k0 + kk) * DM + n0 + nch * 4);
#pragma unroll
        for (int i = 0; i < 4; i++) Bt[nch * 4 + i][kk] = (f16)wv[i];
      }
    }
    __syncthreads();
#pragma unroll
    for (int kc = 0; kc < 2; kc++) {
      f16x8 a[2], b[2];
#pragma unroll
      for (int mi = 0; mi < 2; mi++)
        a[mi] = *(const f16x8*)&As[wr * 32 + mi * 16 + fr][kc * 32 + fs * 8];
#pragma unroll
      for (int ni = 0; ni < 2; ni++)
        b[ni] = *(const f16x8*)&Bt[wc * 32 + ni * 16 + fr][kc * 32 + fs * 8];
#pragma unroll
      for (int mi = 0; mi < 2; mi++)
#pragma unroll
        for (int ni = 0; ni < 2; ni++)
          acc[mi][ni] = __builtin_amdgcn_mfma_f32_16x16x32_f16(a[mi], b[ni], acc[mi][ni], 0, 0, 0);
    }
  }
#pragma unroll
  for (int mi = 0; mi < 2; mi++)
#pragma unroll
    for (int ni = 0; ni < 2; ni++) {
      int gcol = n0 + wc * 32 + ni * 16 + fr;
      float bb = blockIdx.z == 0 ? bias[gcol] : 0.f;
#pragma unroll
      for (int i = 0; i < 4; i++) {
        int grow = m0 + wr * 32 + mi * 16 + fs * 4 + i;
        unsafeAtomicAdd(&out[(size_t)grow * DM + gcol], acc[mi][ni][i] + bb);
      }
    }
}

extern "C" void kernel_launch(void* const* d_in, const int* in_sizes, int n_in,
                              void* d_out, int out_size, void* d_ws, size_t ws_size,
                              hipStream_t stream) {
  const float* q = (const float*)d_in[0];
  const float* k = (const float*)d_in[1];
  const float* v = (const float*)d_in[2];
  const int* mask = (const int*)d_in[3];
  const float* Wq = (const float*)d_in[4];
  const float* bq = (const float*)d_in[5];
  const float* Wk = (const float*)d_in[6];
  const float* bk = (const float*)d_in[7];
  const float* Wv = (const float*)d_in[8];
  const float* bv = (const float*)d_in[9];
  const float* Wo = (const float*)d_in[10];
  const float* bo = (const float*)d_in[11];
  const float* rpe = (const float*)d_in[12];

  char* ws = (char*)d_ws;
  f16* qp = (f16*)(ws);                                  // 4 MB
  f16* kp = (f16*)(ws + (1u << 22));                     // 4 MB
  f16* vpt = (f16*)(ws + (2u << 22));                    // 4 MB [b,h,d,l]
  float* R = (float*)(ws + (3u << 22));                  // 32768*34*4 = 4456448
  unsigned long long* mp64 = (unsigned long long*)(ws + (3u << 22) + 4456448);  // 1 MB
  f16* concat = (f16*)(ws + (3u << 22) + 4456448 + (1u << 20));                 // 4 MB

  float* final_out = (float*)d_out;
  float* attn_out = final_out + (size_t)BS * LQ * DM;

  hipMemsetAsync(final_out, 0, (size_t)BS * LQ * DM * sizeof(float), stream);

  // FIX: cover ALL BS*LQ*LK mask elements (was /32 -> only 3% packed, rest poison)
  maskpack_k<<<dim3(BS * LQ * LK / 256), 256, 0, stream>>>(mask, mp64);

  qkv_k<<<dim3(64, 24), 256, 0, stream>>>(q, k, v, Wq, Wk, Wv, bq, bk, bv, qp, kp, vpt);

  relR_k<<<dim3((BS * H_ * LQ) / 4), 256, 0, stream>>>(qp, rpe, R);

  attn_k<<<dim3(32, 16), 512, 0, stream>>>(qp, kp, vpt, R, (const unsigned*)mp64, attn_out,
                                           concat);

  ogemm_k<<<dim3(64, 8, 2), 256, 0, stream>>>(concat, Wo, bo, final_out);
}